// Round 1
// baseline (667.585 us; speedup 1.0000x reference)
//
#include <hip/hip_runtime.h>
#include <hip/hip_bf16.h>
#include <stdint.h>

#define T_DIM 512
#define IN_DIM 4096
#define OUT_DIM 11008

#define BN 32
#define BK 64
#define KSTEPS (IN_DIM / BK)   // 64
#define NBLK (OUT_DIM / BN)    // 344

typedef __attribute__((ext_vector_type(8))) __bf16 bf16x8;
typedef __attribute__((ext_vector_type(8))) short shortx8;
typedef __attribute__((ext_vector_type(4))) float f32x4;
typedef __attribute__((ext_vector_type(4))) int   intx4;

__device__ __forceinline__ short f32_to_bf16_bits(float f) {
    uint32_t x = __builtin_bit_cast(uint32_t, f);
    x += 0x7FFFu + ((x >> 16) & 1u);   // RTNE; inputs are finite
    return (short)(x >> 16);
}

// ---- quantize activations: xq = sf_decode(sf_encode(x)), stored as bf16 ----
__global__ __launch_bounds__(256) void encode_x_kernel(const float* __restrict__ x,
                                                       short* __restrict__ xq) {
    const float MAXV = 2047.0f / 2048.0f;
    int i = (blockIdx.x * 256 + threadIdx.x) * 8;
    float4 a = *(const float4*)(x + i);
    float4 b = *(const float4*)(x + i + 4);
    float v[8] = {a.x, a.y, a.z, a.w, b.x, b.y, b.z, b.w};
    union { short s[8]; int4 v4; } u;
#pragma unroll
    for (int j = 0; j < 8; ++j) {
        float xv = v[j];
        float ax = fminf(fabsf(xv), MAXV);
        float m = floorf(ax * 2047.0f / MAXV);   // faithful two-step rounding
        float q = m * (1.0f / 2048.0f) * (xv < 0.0f ? 1.0f : -1.0f);
        u.s[j] = f32_to_bf16_bits(q);
    }
    *(int4*)(xq + i) = u.v4;
}

// ---- fused: decode W on the fly + C[512,11008] = A @ W^T + bias ----
// BM = 512 (all T rows) => every weight decoded exactly once.
// 4 waves x (128 rows x 32 cols) each; A-frags direct global->reg (wave-private
// rows, no reuse across waves -> LDS staging of A is pure overhead here).
// W tile 32x64 decoded by all 256 threads into double-buffered, XOR-swizzled LDS.
__global__ __launch_bounds__(256, 2) void fused_dq_gemm_kernel(
    const short* __restrict__ A,      // xq bf16 [512][4096]
    const int*   __restrict__ enc,    // [11008][4096]
    const int*   __restrict__ mask,   // [11008][4096] int32
    const float* __restrict__ wf,     // [11008][4096]
    const float* __restrict__ scale,  // [11008]
    const float* __restrict__ bias,   // [11008]
    float*       __restrict__ C)      // [512][11008]
{
    __shared__ short Ws[2][BN * BK];  // 2 x 4 KB, swizzled

    const int tid  = threadIdx.x;
    const int wave = tid >> 6;
    const int lane = tid & 63;
    const int quad = lane >> 4;
    const int lr   = lane & 15;
    const int wm   = wave * 128;
    const int bn   = blockIdx.x;

    // ---- W-decode mapping: thread owns row (tid>>3), k-slot (tid&7) -> 8 weights/step
    const int wrow = tid >> 3;          // 0..31
    const int q8   = tid & 7;
    const int grow = bn * BN + wrow;
    const float s     = scale[grow];
    const float s2048 = s * (1.0f / 2048.0f);   // fold 1/2048 (exact pow2) into scale
    const int*   ep = enc  + (size_t)grow * IN_DIM + q8 * 8;
    const int*   mp = mask + (size_t)grow * IN_DIM + q8 * 8;
    const float* wp = wf   + (size_t)grow * IN_DIM + q8 * 8;
    // swizzled LDS write addr: slot' = slot ^ (row&7)  (involution, bits 4..6)
    char* wsw_base = (char*)&Ws[0][0] +
        (((wrow * (BK * 2) + q8 * 16) ^ ((wrow & 7) << 4)));

    // ---- A fragment base: lane (lr,quad) reads row wm+mi*16+lr, k quad*8+kf*32
    const short* pa = A + (size_t)(wm + lr) * IN_DIM + quad * 8;

    f32x4 acc[8][2] = {};

    // swizzled Ws fragment read (conflict-free: 16 lanes -> 8 distinct 16B slots, 2-way)
    auto WS_FRAG = [&](int rb, int ni, int kf) -> bf16x8 {
        const int row  = ni * 16 + lr;
        const int byte = ((row * (BK * 2) + quad * 16 + kf * 64) ^ ((row & 7) << 4))
                         + rb * (BN * BK * 2);
        return __builtin_bit_cast(bf16x8, *(const shortx8*)((const char*)&Ws[0][0] + byte));
    };

    // decode 8 weights -> bf16 -> one ds_write_b128 into Ws[wb]
    auto DQW = [&](const intx4 E0, const intx4 E1, const int* mv, const float* wv, int wb) {
        int ev[8] = {E0[0], E0[1], E0[2], E0[3], E1[0], E1[1], E1[2], E1[3]};
        union { short h[8]; int4 q4; } u;
#pragma unroll
        for (int j = 0; j < 8; ++j) {
            // sf_decode: mantissa/2048; sign bit set -> +, clear -> - (faithful)
            float d = (float)(ev[j] & 2047);
            if (!(ev[j] & 2048)) d = -d;
            float v = d * s2048;
            if (mv[j]) v = wv[j] * s;   // outlier: wf * scale (no /2048)
            u.h[j] = f32_to_bf16_bits(v);
        }
        *(int4*)(wsw_base + wb * (BN * BK * 2)) = u.q4;
    };

    // enc/mask double prefetch sets (depth 2; barrier drain guarantees arrival)
    intx4 eA0, eA1, mA0, mA1, eB0, eB1, mB0, mB1;
    eA0 = __builtin_nontemporal_load((const intx4*)(ep));
    eA1 = __builtin_nontemporal_load((const intx4*)(ep + 4));
    mA0 = __builtin_nontemporal_load((const intx4*)(mp));
    mA1 = __builtin_nontemporal_load((const intx4*)(mp + 4));
    eB0 = __builtin_nontemporal_load((const intx4*)(ep + BK));
    eB1 = __builtin_nontemporal_load((const intx4*)(ep + BK + 4));
    mB0 = __builtin_nontemporal_load((const intx4*)(mp + BK));
    mB1 = __builtin_nontemporal_load((const intx4*)(mp + BK + 4));

    {   // prologue: decode step 0 into Ws[0]
        int   mv0[8] = {mA0[0], mA0[1], mA0[2], mA0[3], mA1[0], mA1[1], mA1[2], mA1[3]};
        float wv0[8];
#pragma unroll
        for (int j = 0; j < 8; ++j)
            if (mv0[j]) wv0[j] = wp[j];
        DQW(eA0, eA1, mv0, wv0, 0);
    }
    __syncthreads();

// one K-step: A-frags global->reg, issue em(KT+2), wf loads for (KT+1) early,
// MFMA on Ws[RB] (covers wf latency), decode (KT+1) -> Ws[WB], barrier.
#define STEP(KT, Ei0, Ei1, Mi0, Mi1, Ed0, Ed1, Md0, Md1, RB, WB)                      \
    {                                                                                  \
        const int ko = (KT) * BK;                                                      \
        bf16x8 af[8][2];                                                               \
        _Pragma("unroll")                                                              \
        for (int mi = 0; mi < 8; ++mi) {                                               \
            const short* p = pa + (size_t)mi * (16 * IN_DIM) + ko;                     \
            af[mi][0] = __builtin_bit_cast(bf16x8, *(const shortx8*)(p));              \
            af[mi][1] = __builtin_bit_cast(bf16x8, *(const shortx8*)(p + 32));         \
        }                                                                              \
        if ((KT) + 2 < KSTEPS) {                                                       \
            Ei0 = __builtin_nontemporal_load((const intx4*)(ep + ko + 2 * BK));        \
            Ei1 = __builtin_nontemporal_load((const intx4*)(ep + ko + 2 * BK + 4));    \
            Mi0 = __builtin_nontemporal_load((const intx4*)(mp + ko + 2 * BK));        \
            Mi1 = __builtin_nontemporal_load((const intx4*)(mp + ko + 2 * BK + 4));    \
        }                                                                              \
        int mdv[8]; float wv[8];                                                       \
        if ((KT) + 1 < KSTEPS) {                                                       \
            mdv[0] = Md0[0]; mdv[1] = Md0[1]; mdv[2] = Md0[2]; mdv[3] = Md0[3];        \
            mdv[4] = Md1[0]; mdv[5] = Md1[1]; mdv[6] = Md1[2]; mdv[7] = Md1[3];        \
            _Pragma("unroll")                                                          \
            for (int j = 0; j < 8; ++j)                                                \
                if (mdv[j]) wv[j] = wp[ko + BK + j];                                   \
        }                                                                              \
        _Pragma("unroll")                                                              \
        for (int kf = 0; kf < 2; ++kf) {                                               \
            bf16x8 b0 = WS_FRAG(RB, 0, kf);                                            \
            bf16x8 b1 = WS_FRAG(RB, 1, kf);                                            \
            _Pragma("unroll")                                                          \
            for (int mi = 0; mi < 8; ++mi) {                                           \
                acc[mi][0] = __builtin_amdgcn_mfma_f32_16x16x32_bf16(af[mi][kf], b0,   \
                                                                     acc[mi][0], 0, 0, 0); \
                acc[mi][1] = __builtin_amdgcn_mfma_f32_16x16x32_bf16(af[mi][kf], b1,   \
                                                                     acc[mi][1], 0, 0, 0); \
            }                                                                          \
        }                                                                              \
        if ((KT) + 1 < KSTEPS) DQW(Ed0, Ed1, mdv, wv, WB);                             \
        __syncthreads();                                                               \
    }

    for (int kt = 0; kt < KSTEPS; kt += 2) {
        STEP(kt,     eA0, eA1, mA0, mA1, eB0, eB1, mB0, mB1, 0, 1)
        STEP(kt + 1, eB0, eB1, mB0, mB1, eA0, eA1, mA0, mA1, 1, 0)
    }
#undef STEP

    // epilogue: C/D layout col=lane&15, row=quad*4+reg
    const int rowb = wm + quad * 4;
    const int colb = bn * BN + lr;
#pragma unroll
    for (int ni = 0; ni < 2; ++ni) {
        const int col = colb + ni * 16;
        const float bv = bias[col];
#pragma unroll
        for (int mi = 0; mi < 8; ++mi) {
#pragma unroll
            for (int r = 0; r < 4; ++r) {
                const int row = rowb + mi * 16 + r;
                C[(size_t)row * OUT_DIM + col] = acc[mi][ni][r] + bv;
            }
        }
    }
}

extern "C" void kernel_launch(void* const* d_in, const int* in_sizes, int n_in,
                              void* d_out, int out_size, void* d_ws, size_t ws_size,
                              hipStream_t stream) {
    const float* x     = (const float*)d_in[0];   // [512,4096]
    const float* wfull = (const float*)d_in[1];   // [11008,4096]
    const float* scale = (const float*)d_in[2];   // [11008]
    const float* bias  = (const float*)d_in[3];   // [11008]
    const int*   enc   = (const int*)d_in[4];     // [11008,4096]
    const int*   mask  = (const int*)d_in[5];     // [11008,4096] int32

    float* out = (float*)d_out;
    short* xq  = (short*)d_ws;                    // 512*4096 bf16 = 4 MB

    encode_x_kernel<<<(T_DIM * IN_DIM) / (256 * 8), 256, 0, stream>>>(x, xq);
    fused_dq_gemm_kernel<<<NBLK, 256, 0, stream>>>(xq, enc, mask, wfull, scale, bias, out);
}

// Round 2
// 666.775 us; speedup vs baseline: 1.0012x; 1.0012x over previous
//
#include <hip/hip_runtime.h>
#include <hip/hip_bf16.h>
#include <stdint.h>

#define T_DIM 512
#define IN_DIM 4096
#define OUT_DIM 11008

#define BN 32
#define BK 64
#define KSTEPS (IN_DIM / BK)   // 64
#define NBLK (OUT_DIM / BN)    // 344

typedef __attribute__((ext_vector_type(8))) __bf16 bf16x8;
typedef __attribute__((ext_vector_type(8))) short shortx8;
typedef __attribute__((ext_vector_type(4))) float f32x4;
typedef __attribute__((ext_vector_type(4))) int   intx4;

__device__ __forceinline__ short f32_to_bf16_bits(float f) {
    uint32_t x = __builtin_bit_cast(uint32_t, f);
    x += 0x7FFFu + ((x >> 16) & 1u);   // RTNE; inputs are finite
    return (short)(x >> 16);
}

// ---- quantize activations: xq = sf_decode(sf_encode(x)), stored as bf16 ----
__global__ __launch_bounds__(256) void encode_x_kernel(const float* __restrict__ x,
                                                       short* __restrict__ xq) {
    const float MAXV = 2047.0f / 2048.0f;
    int i = (blockIdx.x * 256 + threadIdx.x) * 8;
    float4 a = *(const float4*)(x + i);
    float4 b = *(const float4*)(x + i + 4);
    float v[8] = {a.x, a.y, a.z, a.w, b.x, b.y, b.z, b.w};
    union { short s[8]; int4 v4; } u;
#pragma unroll
    for (int j = 0; j < 8; ++j) {
        float xv = v[j];
        float ax = fminf(fabsf(xv), MAXV);
        float m = floorf(ax * 2047.0f / MAXV);   // faithful two-step rounding
        float q = m * (1.0f / 2048.0f) * (xv < 0.0f ? 1.0f : -1.0f);
        u.s[j] = f32_to_bf16_bits(q);
    }
    *(int4*)(xq + i) = u.v4;
}

// ---- fused: decode W on the fly + C[512,11008] = A @ W^T + bias ----
// BM = 512 (all T rows) => every weight decoded exactly once (enc/mask single HBM pass).
// 512 threads = 8 waves/block, 2 blocks/CU (VGPR<=128) => 16 waves/CU for latency hiding
// (round 1 at 4 waves/block was starvation-latency-bound: Occupancy 11%, all pipes <10%).
// Wave owns 64 rows x 32 cols. W tile 32x64 decoded into double-buffered swizzled LDS.
__global__ __launch_bounds__(512, 4) void fused_dq_gemm_kernel(
    const short* __restrict__ A,      // xq bf16 [512][4096]
    const int*   __restrict__ enc,    // [11008][4096]
    const int*   __restrict__ mask,   // [11008][4096] int32
    const float* __restrict__ wf,     // [11008][4096]
    const float* __restrict__ scale,  // [11008]
    const float* __restrict__ bias,   // [11008]
    float*       __restrict__ C)      // [512][11008]
{
    __shared__ short Ws[2][BN * BK];  // 2 x 4 KB, XOR-swizzled

    const int tid  = threadIdx.x;
    const int wave = tid >> 6;        // 0..7
    const int lane = tid & 63;
    const int quad = lane >> 4;
    const int lr   = lane & 15;
    const int wm   = wave * 64;       // wave's M-base (64 rows each)
    const int bn   = blockIdx.x;

    // ---- W-decode mapping: thread owns row (tid>>4), k-quad (tid&15) -> 4 weights/step
    const int wrow = tid >> 4;          // 0..31
    const int q4   = tid & 15;          // k-group of 4
    const int grow = bn * BN + wrow;
    const float s     = scale[grow];
    const float s2048 = s * (1.0f / 2048.0f);   // fold 1/2048 (exact pow2) into scale
    const int*   ep = enc  + (size_t)grow * IN_DIM + q4 * 4;
    const int*   mp = mask + (size_t)grow * IN_DIM + q4 * 4;
    const float* wp = wf   + (size_t)grow * IN_DIM + q4 * 4;
    // swizzled LDS write addr (8B group): XOR of 16B-slot bits with row&7
    char* wsw_base = (char*)&Ws[0][0] +
        ((wrow * (BK * 2) + q4 * 8) ^ ((wrow & 7) << 4));

    // ---- A fragment base: lane (lr,quad) reads row wm+mi*16+lr, k = quad*8 + kf*32
    const short* pa = A + (size_t)(wm + lr) * IN_DIM + quad * 8;

    f32x4 acc[4][2] = {};

    // swizzled Ws fragment read (same swizzle as writes; measured 0 bank conflicts r1)
    auto WS_FRAG = [&](int rb, int ni, int kf) -> bf16x8 {
        const int row  = ni * 16 + lr;
        const int byte = ((row * (BK * 2) + quad * 16 + kf * 64) ^ ((row & 7) << 4))
                         + rb * (BN * BK * 2);
        return __builtin_bit_cast(bf16x8, *(const shortx8*)((const char*)&Ws[0][0] + byte));
    };

    // decode 4 weights -> bf16 -> one 8B ds_write into Ws[wb]
    auto DQW = [&](const intx4 E, const int* mv, const float* wv, int wb) {
        union { short h[4]; int2 q2; } u;
#pragma unroll
        for (int j = 0; j < 4; ++j) {
            int ev = E[j];
            // sf_decode: mantissa/2048; sign bit set -> +, clear -> - (faithful)
            float d = (float)(ev & 2047);
            if (!(ev & 2048)) d = -d;
            float v = d * s2048;
            if (mv[j]) v = wv[j] * s;   // outlier: wf * scale (no /2048)
            u.h[j] = f32_to_bf16_bits(v);
        }
        *(int2*)(wsw_base + wb * (BN * BK * 2)) = u.q2;
    };

    // enc/mask double prefetch sets (depth 2; barrier drain guarantees arrival)
    intx4 eA, mA, eB, mB;
    eA = __builtin_nontemporal_load((const intx4*)(ep));
    mA = __builtin_nontemporal_load((const intx4*)(mp));
    eB = __builtin_nontemporal_load((const intx4*)(ep + BK));
    mB = __builtin_nontemporal_load((const intx4*)(mp + BK));

    {   // prologue: decode step 0 into Ws[0]
        int   mv0[4] = {mA[0], mA[1], mA[2], mA[3]};
        float wv0[4];
#pragma unroll
        for (int j = 0; j < 4; ++j)
            if (mv0[j]) wv0[j] = wp[j];
        DQW(eA, mv0, wv0, 0);
    }
    __syncthreads();

// one K-step: A-frags global->reg, prefetch enc/mask(KT+2), wf loads for (KT+1) early,
// MFMA on Ws[RB] (covers load latency), decode (KT+1) -> Ws[WB], barrier.
#define STEP(KT, Ei, Mi, Ed, Md, RB, WB)                                               \
    {                                                                                  \
        const int ko = (KT) * BK;                                                      \
        bf16x8 af[4][2];                                                               \
        _Pragma("unroll")                                                              \
        for (int mi = 0; mi < 4; ++mi) {                                               \
            const short* p = pa + (size_t)mi * (16 * IN_DIM) + ko;                     \
            af[mi][0] = __builtin_bit_cast(bf16x8, *(const shortx8*)(p));              \
            af[mi][1] = __builtin_bit_cast(bf16x8, *(const shortx8*)(p + 32));         \
        }                                                                              \
        if ((KT) + 2 < KSTEPS) {                                                       \
            Ei = __builtin_nontemporal_load((const intx4*)(ep + ko + 2 * BK));         \
            Mi = __builtin_nontemporal_load((const intx4*)(mp + ko + 2 * BK));         \
        }                                                                              \
        int mdv[4]; float wv[4];                                                       \
        if ((KT) + 1 < KSTEPS) {                                                       \
            mdv[0] = Md[0]; mdv[1] = Md[1]; mdv[2] = Md[2]; mdv[3] = Md[3];            \
            _Pragma("unroll")                                                          \
            for (int j = 0; j < 4; ++j)                                                \
                if (mdv[j]) wv[j] = wp[ko + BK + j];                                   \
        }                                                                              \
        _Pragma("unroll")                                                              \
        for (int kf = 0; kf < 2; ++kf) {                                               \
            bf16x8 b0 = WS_FRAG(RB, 0, kf);                                            \
            bf16x8 b1 = WS_FRAG(RB, 1, kf);                                            \
            _Pragma("unroll")                                                          \
            for (int mi = 0; mi < 4; ++mi) {                                           \
                acc[mi][0] = __builtin_amdgcn_mfma_f32_16x16x32_bf16(af[mi][kf], b0,   \
                                                                     acc[mi][0], 0, 0, 0); \
                acc[mi][1] = __builtin_amdgcn_mfma_f32_16x16x32_bf16(af[mi][kf], b1,   \
                                                                     acc[mi][1], 0, 0, 0); \
            }                                                                          \
        }                                                                              \
        if ((KT) + 1 < KSTEPS) DQW(Ed, mdv, wv, WB);                                   \
        __syncthreads();                                                               \
    }

    for (int kt = 0; kt < KSTEPS; kt += 2) {
        STEP(kt,     eA, mA, eB, mB, 0, 1)
        STEP(kt + 1, eB, mB, eA, mA, 1, 0)
    }
#undef STEP

    // epilogue: C/D layout col=lane&15, row=quad*4+reg
    const int rowb = wm + quad * 4;
    const int colb = bn * BN + lr;
#pragma unroll
    for (int ni = 0; ni < 2; ++ni) {
        const int col = colb + ni * 16;
        const float bv = bias[col];
#pragma unroll
        for (int mi = 0; mi < 4; ++mi) {
#pragma unroll
            for (int r = 0; r < 4; ++r) {
                const int row = rowb + mi * 16 + r;
                C[(size_t)row * OUT_DIM + col] = acc[mi][ni][r] + bv;
            }
        }
    }
}

extern "C" void kernel_launch(void* const* d_in, const int* in_sizes, int n_in,
                              void* d_out, int out_size, void* d_ws, size_t ws_size,
                              hipStream_t stream) {
    const float* x     = (const float*)d_in[0];   // [512,4096]
    const float* wfull = (const float*)d_in[1];   // [11008,4096]
    const float* scale = (const float*)d_in[2];   // [11008]
    const float* bias  = (const float*)d_in[3];   // [11008]
    const int*   enc   = (const int*)d_in[4];     // [11008,4096]
    const int*   mask  = (const int*)d_in[5];     // [11008,4096] int32

    float* out = (float*)d_out;
    short* xq  = (short*)d_ws;                    // 512*4096 bf16 = 4 MB

    encode_x_kernel<<<(T_DIM * IN_DIM) / (256 * 8), 256, 0, stream>>>(x, xq);
    fused_dq_gemm_kernel<<<NBLK, 512, 0, stream>>>(xq, enc, mask, wfull, scale, bias, out);
}

// Round 3
// 577.463 us; speedup vs baseline: 1.1561x; 1.1547x over previous
//
#include <hip/hip_runtime.h>
#include <hip/hip_bf16.h>
#include <stdint.h>

#define T_DIM 512
#define IN_DIM 4096
#define OUT_DIM 11008

#define BN 32
#define BK 64
#define KC 4                       // K-split factor: independent chains per output tile
#define KCHUNK (IN_DIM / KC)       // 1024
#define KSTEPS (KCHUNK / BK)       // 16 steps per block
#define NBLK (OUT_DIM / BN)        // 344;  grid = 344 x 4 = 1376 blocks
#define PSZ ((size_t)T_DIM * OUT_DIM)   // partial-C plane, 5,636,096 floats

typedef __attribute__((ext_vector_type(8))) __bf16 bf16x8;
typedef __attribute__((ext_vector_type(8))) short shortx8;
typedef __attribute__((ext_vector_type(4))) float f32x4;
typedef __attribute__((ext_vector_type(4))) int   intx4;

__device__ __forceinline__ short f32_to_bf16_bits(float f) {
    uint32_t x = __builtin_bit_cast(uint32_t, f);
    x += 0x7FFFu + ((x >> 16) & 1u);   // RTNE; inputs are finite
    return (short)(x >> 16);
}

// LDS-only barrier: drain lgkm (ds_write visible, ds_read retired) but leave
// global-load prefetches IN FLIGHT across the barrier (T4: counted vmcnt —
// __syncthreads' vmcnt(0) drain was killing the enc/mask/wf pipelining).
__device__ __forceinline__ void bar_lgkm() {
    asm volatile("s_waitcnt lgkmcnt(0)" ::: "memory");
    __builtin_amdgcn_s_barrier();
}

// ---- quantize activations: xq = sf_decode(sf_encode(x)), stored as bf16 ----
__global__ __launch_bounds__(256) void encode_x_kernel(const float* __restrict__ x,
                                                       short* __restrict__ xq) {
    const float MAXV = 2047.0f / 2048.0f;
    int i = (blockIdx.x * 256 + threadIdx.x) * 8;
    float4 a = *(const float4*)(x + i);
    float4 b = *(const float4*)(x + i + 4);
    float v[8] = {a.x, a.y, a.z, a.w, b.x, b.y, b.z, b.w};
    union { short s[8]; int4 v4; } u;
#pragma unroll
    for (int j = 0; j < 8; ++j) {
        float xv = v[j];
        float ax = fminf(fabsf(xv), MAXV);
        float m = floorf(ax * 2047.0f / MAXV);   // faithful two-step rounding
        float q = m * (1.0f / 2048.0f) * (xv < 0.0f ? 1.0f : -1.0f);
        u.s[j] = f32_to_bf16_bits(q);
    }
    *(int4*)(xq + i) = u.v4;
}

// ---- fused: decode W on the fly + partial C += A-chunk @ Wchunk^T ----
// BM = 512 (all T rows) => every weight decoded exactly once (enc/mask single pass).
// K-split x4: block (bn, kc) handles k in [kc*1024, (kc+1)*1024) -> 1376 independent
// blocks (r2 lesson: barrier-locked block is the serial unit; 344 blocks = 1.3/CU was
// the bottleneck, not waves-per-block). Partials summed by reduce_kernel.
__global__ __launch_bounds__(512, 4) void fused_dq_gemm_kernel(
    const short* __restrict__ A,      // xq bf16 [512][4096]
    const int*   __restrict__ enc,    // [11008][4096]
    const int*   __restrict__ mask,   // [11008][4096] int32
    const float* __restrict__ wf,     // [11008][4096]
    const float* __restrict__ scale,  // [11008]
    float*       __restrict__ Cp)     // [KC][512][11008] partials
{
    __shared__ short Ws[2][BN * BK];  // 2 x 4 KB, XOR-swizzled

    const int tid  = threadIdx.x;
    const int wave = tid >> 6;        // 0..7
    const int lane = tid & 63;
    const int quad = lane >> 4;
    const int lr   = lane & 15;
    const int wm   = wave * 64;       // wave's M-base (64 rows each)
    const int bn   = blockIdx.x;
    const int kc   = blockIdx.y;
    const int kbase = kc * KCHUNK;

    // ---- W-decode mapping: thread owns row (tid>>4), k-quad (tid&15) -> 4 weights/step
    const int wrow = tid >> 4;          // 0..31
    const int q4   = tid & 15;          // k-group of 4
    const int grow = bn * BN + wrow;
    const float s     = scale[grow];
    const float s2048 = s * (1.0f / 2048.0f);   // fold 1/2048 (exact pow2) into scale
    const int*   ep = enc  + (size_t)grow * IN_DIM + kbase + q4 * 4;
    const int*   mp = mask + (size_t)grow * IN_DIM + kbase + q4 * 4;
    const float* wp = wf   + (size_t)grow * IN_DIM + kbase + q4 * 4;
    // swizzled LDS write addr (8B group): XOR of 16B-slot bits with row&7
    char* wsw_base = (char*)&Ws[0][0] +
        ((wrow * (BK * 2) + q4 * 8) ^ ((wrow & 7) << 4));

    // ---- A fragment base: lane (lr,quad) reads row wm+mi*16+lr, k = quad*8 + kf*32
    const short* pa = A + (size_t)(wm + lr) * IN_DIM + kbase + quad * 8;

    f32x4 acc[4][2] = {};

    // swizzled Ws fragment read (same swizzle as writes; 0 bank conflicts measured)
    auto WS_FRAG = [&](int rb, int ni, int kf) -> bf16x8 {
        const int row  = ni * 16 + lr;
        const int byte = ((row * (BK * 2) + quad * 16 + kf * 64) ^ ((row & 7) << 4))
                         + rb * (BN * BK * 2);
        return __builtin_bit_cast(bf16x8, *(const shortx8*)((const char*)&Ws[0][0] + byte));
    };

    // decode 4 weights -> bf16 -> one 8B ds_write into Ws[wb]
    auto DQW = [&](const intx4 E, const int* mv, const float* wv, int wb) {
        union { short h[4]; int2 q2; } u;
#pragma unroll
        for (int j = 0; j < 4; ++j) {
            int ev = E[j];
            // sf_decode: mantissa/2048; sign bit set -> +, clear -> - (faithful)
            float d = (float)(ev & 2047);
            if (!(ev & 2048)) d = -d;
            float v = d * s2048;
            if (mv[j]) v = wv[j] * s;   // outlier: wf * scale (no /2048)
            u.h[j] = f32_to_bf16_bits(v);
        }
        *(int2*)(wsw_base + wb * (BN * BK * 2)) = u.q2;
    };

    // enc/mask double prefetch sets (depth 2, stays in flight across raw barriers)
    intx4 eA, mA, eB, mB;
    eA = __builtin_nontemporal_load((const intx4*)(ep));
    mA = __builtin_nontemporal_load((const intx4*)(mp));
    eB = __builtin_nontemporal_load((const intx4*)(ep + BK));
    mB = __builtin_nontemporal_load((const intx4*)(mp + BK));

    {   // prologue: decode step 0 into Ws[0]
        int   mv0[4] = {mA[0], mA[1], mA[2], mA[3]};
        float wv0[4];
#pragma unroll
        for (int j = 0; j < 4; ++j)
            if (mv0[j]) wv0[j] = wp[j];
        DQW(eA, mv0, wv0, 0);
    }
    __syncthreads();

// one K-step: A-frags global->reg, prefetch enc/mask(KT+2), wf loads for (KT+1) early,
// MFMA on Ws[RB] (covers load latency), decode (KT+1) -> Ws[WB], lgkm-only barrier
// (vmem prefetches NOT drained -- compiler inserts counted vmcnt before uses).
#define STEP(KT, Ei, Mi, Ed, Md, RB, WB)                                               \
    {                                                                                  \
        const int ko = (KT) * BK;                                                      \
        bf16x8 af[4][2];                                                               \
        _Pragma("unroll")                                                              \
        for (int mi = 0; mi < 4; ++mi) {                                               \
            const short* p = pa + (size_t)mi * (16 * IN_DIM) + ko;                     \
            af[mi][0] = __builtin_bit_cast(bf16x8, *(const shortx8*)(p));              \
            af[mi][1] = __builtin_bit_cast(bf16x8, *(const shortx8*)(p + 32));         \
        }                                                                              \
        if ((KT) + 2 < KSTEPS) {                                                       \
            Ei = __builtin_nontemporal_load((const intx4*)(ep + ko + 2 * BK));         \
            Mi = __builtin_nontemporal_load((const intx4*)(mp + ko + 2 * BK));         \
        }                                                                              \
        int mdv[4]; float wv[4];                                                       \
        if ((KT) + 1 < KSTEPS) {                                                       \
            mdv[0] = Md[0]; mdv[1] = Md[1]; mdv[2] = Md[2]; mdv[3] = Md[3];            \
            _Pragma("unroll")                                                          \
            for (int j = 0; j < 4; ++j)                                                \
                if (mdv[j]) wv[j] = wp[ko + BK + j];                                   \
        }                                                                              \
        _Pragma("unroll")                                                              \
        for (int kf = 0; kf < 2; ++kf) {                                               \
            bf16x8 b0 = WS_FRAG(RB, 0, kf);                                            \
            bf16x8 b1 = WS_FRAG(RB, 1, kf);                                            \
            _Pragma("unroll")                                                          \
            for (int mi = 0; mi < 4; ++mi) {                                           \
                acc[mi][0] = __builtin_amdgcn_mfma_f32_16x16x32_bf16(af[mi][kf], b0,   \
                                                                     acc[mi][0], 0, 0, 0); \
                acc[mi][1] = __builtin_amdgcn_mfma_f32_16x16x32_bf16(af[mi][kf], b1,   \
                                                                     acc[mi][1], 0, 0, 0); \
            }                                                                          \
        }                                                                              \
        if ((KT) + 1 < KSTEPS) DQW(Ed, mdv, wv, WB);                                   \
        bar_lgkm();                                                                    \
    }

    for (int kt = 0; kt < KSTEPS; kt += 2) {
        STEP(kt,     eA, mA, eB, mB, 0, 1)
        STEP(kt + 1, eB, mB, eA, mA, 1, 0)
    }
#undef STEP

    // epilogue: partial C (no bias; reduce_kernel adds it). layout col=lane&15,
    // row=quad*4+reg
    float* pc = Cp + (size_t)kc * PSZ;
    const int rowb = wm + quad * 4;
    const int colb = bn * BN + lr;
#pragma unroll
    for (int ni = 0; ni < 2; ++ni) {
        const int col = colb + ni * 16;
#pragma unroll
        for (int mi = 0; mi < 4; ++mi) {
#pragma unroll
            for (int r = 0; r < 4; ++r) {
                const int row = rowb + mi * 16 + r;
                pc[(size_t)row * OUT_DIM + col] = acc[mi][ni][r];
            }
        }
    }
}

// ---- C = p0+p1+p2+p3 + bias ----
__global__ __launch_bounds__(256) void reduce_kernel(const float* __restrict__ P,
                                                     const float* __restrict__ bias,
                                                     float* __restrict__ C) {
    size_t i = ((size_t)blockIdx.x * 256 + threadIdx.x) * 4;
    int col = (int)(i % OUT_DIM);           // OUT_DIM % 4 == 0 -> aligned float4
    float4 s0 = *(const float4*)(P + i);
    float4 s1 = *(const float4*)(P + PSZ + i);
    float4 s2 = *(const float4*)(P + 2 * PSZ + i);
    float4 s3 = *(const float4*)(P + 3 * PSZ + i);
    float4 b  = *(const float4*)(bias + col);
    float4 o;
    o.x = s0.x + s1.x + s2.x + s3.x + b.x;
    o.y = s0.y + s1.y + s2.y + s3.y + b.y;
    o.z = s0.z + s1.z + s2.z + s3.z + b.z;
    o.w = s0.w + s1.w + s2.w + s3.w + b.w;
    *(float4*)(C + i) = o;
}

extern "C" void kernel_launch(void* const* d_in, const int* in_sizes, int n_in,
                              void* d_out, int out_size, void* d_ws, size_t ws_size,
                              hipStream_t stream) {
    const float* x     = (const float*)d_in[0];   // [512,4096]
    const float* wfull = (const float*)d_in[1];   // [11008,4096]
    const float* scale = (const float*)d_in[2];   // [11008]
    const float* bias  = (const float*)d_in[3];   // [11008]
    const int*   enc   = (const int*)d_in[4];     // [11008,4096]
    const int*   mask  = (const int*)d_in[5];     // [11008,4096] int32

    float* out = (float*)d_out;
    short* xq  = (short*)d_ws;                            // 4,194,304 B
    float* Cp  = (float*)((char*)d_ws + (size_t)T_DIM * IN_DIM * 2);  // 4 x 22.5 MB
    // total workspace = 4,194,304 + 90,177,536 = 94,371,840 B (same as r0 footprint)

    encode_x_kernel<<<(T_DIM * IN_DIM) / (256 * 8), 256, 0, stream>>>(x, xq);
    dim3 grid(NBLK, KC);   // 344 x 4 = 1376 blocks
    fused_dq_gemm_kernel<<<grid, 512, 0, stream>>>(xq, enc, mask, wfull, scale, Cp);
    reduce_kernel<<<(int)(PSZ / (256 * 4)), 256, 0, stream>>>(Cp, bias, out);
}